// Round 5
// baseline (21.224 us; speedup 1.0000x reference)
//
#include <hip/hip_runtime.h>
#include <hip/hip_bf16.h>
#include <math.h>

// Problem constants
#define BB 8
#define NN 1024
#define TT 512
#define KK 9
#define HH 32

#define TSLICE 16           // t-columns per render block
#define GGRP   64           // n-groups per render block (g = tid>>2)
#define NITER  (NN/GGRP)    // 16 n per thread

__constant__ float c_epos[KK][3] = {
    { 0.30f,  0.25f, 0.00f},
    {-0.30f,  0.25f, 0.00f},
    {-0.05f, -0.40f, 0.00f},
    { 0.03f,  0.05f, 0.20f},
    { 0.00f,  0.05f, 0.22f},
    {-0.04f,  0.01f, 0.21f},
    {-0.08f, -0.02f, 0.18f},
    {-0.14f, -0.02f, 0.13f},
    {-0.20f, -0.02f, 0.07f},
};

// Kernel 1: A[b,n,k] = amp * (dd . r_vec) * corr / (r2+0.04)^1.5  (295 KB)
__global__ __launch_bounds__(256) void coef_kernel(
    const float* __restrict__ pos,   // (B,N,3)
    const float* __restrict__ dd,    // (B,N,3)
    const float* __restrict__ amp,   // (B,N)
    const float* __restrict__ eoff,  // (B,K,3)
    const float* __restrict__ W1,    // (H,7)
    const float* __restrict__ pb1,   // (H)
    const float* __restrict__ W2,    // (1,H)
    const float* __restrict__ pb2,   // (1)
    float* __restrict__ A)           // (B,N,K)
{
    __shared__ float sW1[HH * 7];
    __shared__ float sb1[HH];
    __shared__ float sW2[HH];
    const int tid = threadIdx.x;
    if (tid < HH * 7) sW1[tid] = W1[tid];
    if (tid < HH)     { sb1[tid] = pb1[tid]; sW2[tid] = W2[tid]; }
    __syncthreads();

    const int idx = blockIdx.x * 256 + tid;     // = bn*9 + k, total 73728
    if (idx >= BB * NN * KK) return;
    const int k  = idx % KK;
    const int bn = idx / KK;
    const int b  = bn / NN;

    const float px = pos[bn * 3 + 0];
    const float py = pos[bn * 3 + 1];
    const float pz = pos[bn * 3 + 2];

    const float ex = c_epos[k][0] + eoff[(b * KK + k) * 3 + 0];
    const float ey = c_epos[k][1] + eoff[(b * KK + k) * 3 + 1];
    const float ez = c_epos[k][2] + eoff[(b * KK + k) * 3 + 2];

    const float rx = ex - px, ry = ey - py, rz = ez - pz;
    const float r2 = rx * rx + ry * ry + rz * rz;
    const float d0 = r2 + 0.04f;
    const float denom = d0 * sqrtf(d0);

    const float rdist = fmaxf(sqrtf(r2), 1e-6f);
    const float rinv  = 1.0f / rdist;
    float feat[7];
    feat[0] = px; feat[1] = py; feat[2] = pz;
    feat[3] = rx * rinv; feat[4] = ry * rinv; feat[5] = rz * rinv;
    feat[6] = rdist;

    float raw = pb2[0];
    #pragma unroll
    for (int j = 0; j < HH; ++j) {
        float s = sb1[j];
        #pragma unroll
        for (int f = 0; f < 7; ++f) s += sW1[j * 7 + f] * feat[f];
        const float g = 0.5f * s * (1.0f + erff(s * 0.70710678118654752f));
        raw += sW2[j] * g;
    }
    const float corr = 1.0f + 0.5f * tanhf(raw);

    const float ddx = dd[bn * 3 + 0], ddy = dd[bn * 3 + 1], ddz = dd[bn * 3 + 2];
    const float dot = ddx * rx + ddy * ry + ddz * rz;

    A[idx] = amp[bn] * dot * corr / denom;
}

// Kernel 2: render — per block (t-slice, b): stage A[b] in LDS, accumulate
// V[b,k,t] over ALL n in-block, clip, compute leads, write final outputs.
__global__ __launch_bounds__(256) void render_kernel(
    const float* __restrict__ A,     // (B,N,K)
    const float* __restrict__ env,   // (B,N,T)
    float* __restrict__ out)         // v_leads (B,12,T) ++ V_elec (B,K,T)
{
    const int tid   = threadIdx.x;
    const int b     = blockIdx.y;
    const int t0    = blockIdx.x * TSLICE;
    const int tlane = tid & 3;       // 4 t-columns each (float4)
    const int g     = tid >> 2;      // 0..63 n-group

    __shared__ float sA[NN][12];     // rows padded to 48 B: b128-aligned, 2-way banks
    __shared__ float sV[4][KK][TSLICE];
    __shared__ float sR[KK][TSLICE];

    // ---- stage A[b] (36 KB, from L2/L3) ----
    const float* Ab = A + (size_t)b * NN * KK;
    for (int j = tid; j < NN * KK; j += 256) {
        const int n = j / 9;
        const int k = j - n * 9;
        sA[n][k] = Ab[j];
    }
    __syncthreads();

    // ---- accumulate: thread owns 4 t, n = g + 64*i ----
    float4 acc[KK];
    #pragma unroll
    for (int k = 0; k < KK; ++k) acc[k] = make_float4(0.f, 0.f, 0.f, 0.f);

    const float* envb = env + ((size_t)b * NN) * TT + t0 + 4 * tlane;
    #pragma unroll
    for (int i = 0; i < NITER; ++i) {
        const int n = g + GGRP * i;
        const float4 ev = *(const float4*)(envb + (size_t)n * TT);
        const float4 a0 = *(const float4*)&sA[n][0];
        const float4 a1 = *(const float4*)&sA[n][4];
        const float  a8 = sA[n][8];
        acc[0].x += a0.x * ev.x; acc[0].y += a0.x * ev.y; acc[0].z += a0.x * ev.z; acc[0].w += a0.x * ev.w;
        acc[1].x += a0.y * ev.x; acc[1].y += a0.y * ev.y; acc[1].z += a0.y * ev.z; acc[1].w += a0.y * ev.w;
        acc[2].x += a0.z * ev.x; acc[2].y += a0.z * ev.y; acc[2].z += a0.z * ev.z; acc[2].w += a0.z * ev.w;
        acc[3].x += a0.w * ev.x; acc[3].y += a0.w * ev.y; acc[3].z += a0.w * ev.z; acc[3].w += a0.w * ev.w;
        acc[4].x += a1.x * ev.x; acc[4].y += a1.x * ev.y; acc[4].z += a1.x * ev.z; acc[4].w += a1.x * ev.w;
        acc[5].x += a1.y * ev.x; acc[5].y += a1.y * ev.y; acc[5].z += a1.y * ev.z; acc[5].w += a1.y * ev.w;
        acc[6].x += a1.z * ev.x; acc[6].y += a1.z * ev.y; acc[6].z += a1.z * ev.z; acc[6].w += a1.z * ev.w;
        acc[7].x += a1.w * ev.x; acc[7].y += a1.w * ev.y; acc[7].z += a1.w * ev.z; acc[7].w += a1.w * ev.w;
        acc[8].x += a8   * ev.x; acc[8].y += a8   * ev.y; acc[8].z += a8   * ev.z; acc[8].w += a8   * ev.w;
    }

    // ---- intra-wave butterfly over g&15 (lane bits 2..5) ----
    #pragma unroll
    for (int k = 0; k < KK; ++k) {
        #pragma unroll
        for (int m = 4; m <= 32; m <<= 1) {
            acc[k].x += __shfl_xor(acc[k].x, m, 64);
            acc[k].y += __shfl_xor(acc[k].y, m, 64);
            acc[k].z += __shfl_xor(acc[k].z, m, 64);
            acc[k].w += __shfl_xor(acc[k].w, m, 64);
        }
    }
    const int w = tid >> 6;          // wave id 0..3
    if ((tid & 63) < 4) {            // lane == tlane holds the wave sum
        #pragma unroll
        for (int k = 0; k < KK; ++k) {
            sV[w][k][tlane * 4 + 0] = acc[k].x;
            sV[w][k][tlane * 4 + 1] = acc[k].y;
            sV[w][k][tlane * 4 + 2] = acc[k].z;
            sV[w][k][tlane * 4 + 3] = acc[k].w;
        }
    }
    __syncthreads();

    // ---- cross-wave reduce + clip ----
    if (tid < KK * TSLICE) {
        const int k  = tid / TSLICE;
        const int tc = tid - k * TSLICE;
        const float v = sV[0][k][tc] + sV[1][k][tc] + sV[2][k][tc] + sV[3][k][tc];
        sR[k][tc] = fminf(fmaxf(v, -50.0f), 50.0f);
    }
    __syncthreads();

    // ---- leads + outputs ----
    if (tid < TSLICE) {
        const int t = t0 + tid;
        float V[KK];
        #pragma unroll
        for (int k = 0; k < KK; ++k) V[k] = sR[k][tid];

        float* vleads = out;                        // (B,12,T)
        float* velec  = out + (size_t)BB * 12 * TT; // (B,K,T)

        #pragma unroll
        for (int k = 0; k < KK; ++k)
            velec[((size_t)b * KK + k) * TT + t] = V[k];

        const float RA = V[0], LA = V[1], LL = V[2];
        const float WCT = (RA + LA + LL) * (1.0f / 3.0f);

        float L[12];
        L[0] = LA - RA;
        L[1] = LL - RA;
        L[2] = LL - LA;
        L[3] = RA - 0.5f * (LA + LL);
        L[4] = LA - 0.5f * (RA + LL);
        L[5] = LL - 0.5f * (RA + LA);
        L[6]  = V[3] - WCT;
        L[7]  = V[4] - WCT;
        L[8]  = V[5] - WCT;
        L[9]  = V[6] - WCT;
        L[10] = V[7] - WCT;
        L[11] = V[8] - WCT;

        #pragma unroll
        for (int l = 0; l < 12; ++l)
            vleads[((size_t)b * 12 + l) * TT + t] = L[l];
    }
}

extern "C" void kernel_launch(void* const* d_in, const int* in_sizes, int n_in,
                              void* d_out, int out_size, void* d_ws, size_t ws_size,
                              hipStream_t stream) {
    const float* pos  = (const float*)d_in[0];
    const float* dd   = (const float*)d_in[1];
    const float* amp  = (const float*)d_in[2];
    const float* env  = (const float*)d_in[3];
    const float* eoff = (const float*)d_in[4];
    const float* W1   = (const float*)d_in[5];
    const float* b1   = (const float*)d_in[6];
    const float* W2   = (const float*)d_in[7];
    const float* b2   = (const float*)d_in[8];
    float* out = (float*)d_out;

    float* A = (float*)d_ws;   // (B,N,K) floats = 295 KB

    {
        const int total = BB * NN * KK;               // 73728
        coef_kernel<<<(total + 255) / 256, 256, 0, stream>>>(
            pos, dd, amp, eoff, W1, b1, W2, b2, A);
    }
    {
        dim3 grid(TT / TSLICE, BB);                   // 32 x 8 = 256 blocks
        render_kernel<<<grid, 256, 0, stream>>>(A, env, out);
    }
}

// Round 6
// 20.016 us; speedup vs baseline: 1.0603x; 1.0603x over previous
//
#include <hip/hip_runtime.h>
#include <hip/hip_bf16.h>
#include <math.h>

// Problem constants
#define BB 8
#define NN 1024
#define TT 512
#define KK 9
#define HH 32

#define NCHUNK 64          // n-chunks (grid.x of phase A)
#define NPER   (NN/NCHUNK) // 16 n per chunk

__constant__ float c_epos[KK][3] = {
    { 0.30f,  0.25f, 0.00f},
    {-0.30f,  0.25f, 0.00f},
    {-0.05f, -0.40f, 0.00f},
    { 0.03f,  0.05f, 0.20f},
    { 0.00f,  0.05f, 0.22f},
    {-0.04f,  0.01f, 0.21f},
    {-0.08f, -0.02f, 0.18f},
    {-0.14f, -0.02f, 0.13f},
    {-0.20f, -0.02f, 0.07f},
};

// Phase A: block (chunk, b) computes A[b, n0:n0+16, :] via MLP into LDS,
// then partial[c,b,k,0:512] over its 16 n. Each thread owns 2 t (float2).
__global__ __launch_bounds__(256) void fused_kernel(
    const float* __restrict__ pos,   // (B,N,3)
    const float* __restrict__ dd,    // (B,N,3)
    const float* __restrict__ amp,   // (B,N)
    const float* __restrict__ env,   // (B,N,T)
    const float* __restrict__ eoff,  // (B,K,3)
    const float* __restrict__ W1,    // (H,7)
    const float* __restrict__ pb1,   // (H)
    const float* __restrict__ W2,    // (1,H)
    const float* __restrict__ pb2,   // (1)
    float* __restrict__ partial)     // (NCHUNK,B,K,T)
{
    const int tid   = threadIdx.x;
    const int chunk = blockIdx.x;
    const int b     = blockIdx.y;
    const int n0    = chunk * NPER;

    __shared__ float sW1[HH * 7];
    __shared__ float sb1[HH];
    __shared__ float sW2[HH];
    __shared__ float sb2;
    __shared__ float sE[KK][3];
    __shared__ float sA[NPER][12];   // 9 coeffs padded to 12 for float4 reads

    if (tid < HH * 7) sW1[tid] = W1[tid];
    if (tid < HH)     { sb1[tid] = pb1[tid]; sW2[tid] = W2[tid]; }
    if (tid < KK * 3) sE[tid / 3][tid % 3] = c_epos[tid / 3][tid % 3] + eoff[b * KK * 3 + tid];
    if (tid == 0)     sb2 = pb2[0];
    __syncthreads();

    if (tid < NPER * KK) {           // 144 MLP evals, one per thread
        const int k  = tid % KK;
        const int nl = tid / KK;
        const int bn = b * NN + n0 + nl;

        const float px = pos[bn * 3 + 0];
        const float py = pos[bn * 3 + 1];
        const float pz = pos[bn * 3 + 2];

        const float rx = sE[k][0] - px, ry = sE[k][1] - py, rz = sE[k][2] - pz;
        const float r2 = rx * rx + ry * ry + rz * rz;
        const float d0 = r2 + 0.04f;
        const float denom = d0 * sqrtf(d0);

        const float rdist = fmaxf(sqrtf(r2), 1e-6f);
        const float rinv  = 1.0f / rdist;
        float feat[7];
        feat[0] = px; feat[1] = py; feat[2] = pz;
        feat[3] = rx * rinv; feat[4] = ry * rinv; feat[5] = rz * rinv;
        feat[6] = rdist;

        float raw = sb2;
        #pragma unroll
        for (int j = 0; j < HH; ++j) {
            float s = sb1[j];
            #pragma unroll
            for (int f = 0; f < 7; ++f) s += sW1[j * 7 + f] * feat[f];
            const float g = 0.5f * s * (1.0f + erff(s * 0.70710678118654752f));
            raw += sW2[j] * g;
        }
        const float corr = 1.0f + 0.5f * tanhf(raw);

        const float ddx = dd[bn * 3 + 0], ddy = dd[bn * 3 + 1], ddz = dd[bn * 3 + 2];
        const float dot = ddx * rx + ddy * ry + ddz * rz;

        sA[nl][k] = amp[bn] * dot * corr / denom;
    }
    __syncthreads();

    // Main loop: thread owns t = {2*tid, 2*tid+1}; 16 rows, fully unrolled.
    float2 acc[KK];
    #pragma unroll
    for (int k = 0; k < KK; ++k) { acc[k].x = 0.0f; acc[k].y = 0.0f; }

    const float2* envp = (const float2*)(env + ((size_t)(b * NN + n0)) * TT) + tid;
    const float4* s4 = (const float4*)sA;
    #pragma unroll
    for (int nl = 0; nl < NPER; ++nl) {
        const float2 ev = envp[(size_t)nl * (TT / 2)];
        const float4 a0 = s4[nl * 3 + 0];
        const float4 a1 = s4[nl * 3 + 1];
        const float  a8 = sA[nl][8];
        acc[0].x += a0.x * ev.x; acc[0].y += a0.x * ev.y;
        acc[1].x += a0.y * ev.x; acc[1].y += a0.y * ev.y;
        acc[2].x += a0.z * ev.x; acc[2].y += a0.z * ev.y;
        acc[3].x += a0.w * ev.x; acc[3].y += a0.w * ev.y;
        acc[4].x += a1.x * ev.x; acc[4].y += a1.x * ev.y;
        acc[5].x += a1.y * ev.x; acc[5].y += a1.y * ev.y;
        acc[6].x += a1.z * ev.x; acc[6].y += a1.z * ev.y;
        acc[7].x += a1.w * ev.x; acc[7].y += a1.w * ev.y;
        acc[8].x += a8   * ev.x; acc[8].y += a8   * ev.y;
    }

    float2* pp = (float2*)(partial + (((size_t)chunk * BB + b) * KK) * TT) + tid;
    #pragma unroll
    for (int k = 0; k < KK; ++k) pp[(size_t)k * (TT / 2)] = acc[k];
}

// Finalize: V = clip(sum_c partial, -50, 50); emit leads + V_electrodes.
// grid (16, 8): block covers 32 t; 32 c-groups x 8 float4-slots over t.
__global__ __launch_bounds__(256) void finalize_kernel(
    const float* __restrict__ partial,  // (NCHUNK,B,K,T)
    float* __restrict__ out)            // v_leads (B,12,T) then V_elec (B,K,T)
{
    const int tid = threadIdx.x;
    const int tl4 = tid & 7;        // float4 slot: t = t0 + tl4*4 .. +3
    const int cg  = tid >> 3;       // 0..31
    const int tc  = blockIdx.x;     // 0..15
    const int b   = blockIdx.y;
    const int t0  = tc * 32;

    float4 s[KK];
    #pragma unroll
    for (int k = 0; k < KK; ++k) s[k] = make_float4(0.f, 0.f, 0.f, 0.f);

    #pragma unroll
    for (int ci = 0; ci < 2; ++ci) {
        const int c = cg + 32 * ci;
        const float* base = partial + (((size_t)c * BB + b) * KK) * TT + t0 + tl4 * 4;
        #pragma unroll
        for (int k = 0; k < KK; ++k) {
            const float4 v = *(const float4*)(base + (size_t)k * TT);
            s[k].x += v.x; s[k].y += v.y; s[k].z += v.z; s[k].w += v.w;
        }
    }

    __shared__ float4 sV[32][KK][8];   // 36 KB
    __shared__ float  sRf[KK][32];
    #pragma unroll
    for (int k = 0; k < KK; ++k) sV[cg][k][tl4] = s[k];
    __syncthreads();

    if (tid < KK * 8) {                // 72 threads: reduce 32 c-groups
        const int k  = tid >> 3;
        const int tl = tid & 7;
        float4 v = make_float4(0.f, 0.f, 0.f, 0.f);
        #pragma unroll
        for (int g = 0; g < 32; ++g) {
            const float4 u = sV[g][k][tl];
            v.x += u.x; v.y += u.y; v.z += u.z; v.w += u.w;
        }
        sRf[k][tl * 4 + 0] = fminf(fmaxf(v.x, -50.0f), 50.0f);
        sRf[k][tl * 4 + 1] = fminf(fmaxf(v.y, -50.0f), 50.0f);
        sRf[k][tl * 4 + 2] = fminf(fmaxf(v.z, -50.0f), 50.0f);
        sRf[k][tl * 4 + 3] = fminf(fmaxf(v.w, -50.0f), 50.0f);
    }
    __syncthreads();

    if (tid < 32) {
        const int t = t0 + tid;
        float V[KK];
        #pragma unroll
        for (int k = 0; k < KK; ++k) V[k] = sRf[k][tid];

        float* vleads = out;                        // (B,12,T)
        float* velec  = out + (size_t)BB * 12 * TT; // (B,K,T)

        #pragma unroll
        for (int k = 0; k < KK; ++k)
            velec[((size_t)b * KK + k) * TT + t] = V[k];

        const float RA = V[0], LA = V[1], LL = V[2];
        const float WCT = (RA + LA + LL) * (1.0f / 3.0f);

        float L[12];
        L[0] = LA - RA;
        L[1] = LL - RA;
        L[2] = LL - LA;
        L[3] = RA - 0.5f * (LA + LL);
        L[4] = LA - 0.5f * (RA + LL);
        L[5] = LL - 0.5f * (RA + LA);
        L[6]  = V[3] - WCT;
        L[7]  = V[4] - WCT;
        L[8]  = V[5] - WCT;
        L[9]  = V[6] - WCT;
        L[10] = V[7] - WCT;
        L[11] = V[8] - WCT;

        #pragma unroll
        for (int l = 0; l < 12; ++l)
            vleads[((size_t)b * 12 + l) * TT + t] = L[l];
    }
}

extern "C" void kernel_launch(void* const* d_in, const int* in_sizes, int n_in,
                              void* d_out, int out_size, void* d_ws, size_t ws_size,
                              hipStream_t stream) {
    const float* pos  = (const float*)d_in[0];
    const float* dd   = (const float*)d_in[1];
    const float* amp  = (const float*)d_in[2];
    const float* env  = (const float*)d_in[3];
    const float* eoff = (const float*)d_in[4];
    const float* W1   = (const float*)d_in[5];
    const float* b1   = (const float*)d_in[6];
    const float* W2   = (const float*)d_in[7];
    const float* b2   = (const float*)d_in[8];
    float* out = (float*)d_out;

    float* partial = (float*)d_ws;   // (NCHUNK,B,K,T) floats = 9.4 MB

    {
        dim3 grid(NCHUNK, BB);           // 64 x 8 = 512 blocks
        fused_kernel<<<grid, 256, 0, stream>>>(
            pos, dd, amp, env, eoff, W1, b1, W2, b2, partial);
    }
    {
        dim3 grid(16, BB);               // 128 blocks
        finalize_kernel<<<grid, 256, 0, stream>>>(partial, out);
    }
}

// Round 7
// 18.615 us; speedup vs baseline: 1.1401x; 1.0752x over previous
//
#include <hip/hip_runtime.h>
#include <hip/hip_bf16.h>
#include <math.h>

// Problem constants
#define BB 8
#define NN 1024
#define TT 512
#define KK 9
#define HH 32

#define NCHUNK 32          // n-chunks (grid.x of phase A)
#define NPER   (NN/NCHUNK) // 32 n per chunk (2 groups of 16)

__constant__ float c_epos[KK][3] = {
    { 0.30f,  0.25f, 0.00f},
    {-0.30f,  0.25f, 0.00f},
    {-0.05f, -0.40f, 0.00f},
    { 0.03f,  0.05f, 0.20f},
    { 0.00f,  0.05f, 0.22f},
    {-0.04f,  0.01f, 0.21f},
    {-0.08f, -0.02f, 0.18f},
    {-0.14f, -0.02f, 0.13f},
    {-0.20f, -0.02f, 0.07f},
};

// Phase A: block (chunk, b), 512 threads = 2 n-groups x 256 t-pair threads.
// Computes A[b, n0:n0+32, :] via MLP into LDS (1x, no redundancy), then each
// group accumulates 16 n over its t-pair, cross-reduces in LDS, writes
// partial[c,b,k,t].
__global__ __launch_bounds__(512) void fused_kernel(
    const float* __restrict__ pos,   // (B,N,3)
    const float* __restrict__ dd,    // (B,N,3)
    const float* __restrict__ amp,   // (B,N)
    const float* __restrict__ env,   // (B,N,T)
    const float* __restrict__ eoff,  // (B,K,3)
    const float* __restrict__ W1,    // (H,7)
    const float* __restrict__ pb1,   // (H)
    const float* __restrict__ W2,    // (1,H)
    const float* __restrict__ pb2,   // (1)
    float* __restrict__ partial)     // (NCHUNK,B,K,T)
{
    const int tid   = threadIdx.x;
    const int chunk = blockIdx.x;
    const int b     = blockIdx.y;
    const int n0    = chunk * NPER;
    const int ng    = tid >> 8;      // n-group 0/1 (16 n each)
    const int tp    = tid & 255;     // t-pair index (t = 2*tp, 2*tp+1)

    __shared__ float sW1[HH * 7];
    __shared__ float sb1[HH];
    __shared__ float sW2[HH];
    __shared__ float sb2;
    __shared__ float sE[KK][3];
    __shared__ float sA[NPER][12];       // 9 coeffs padded to 12 for float4 reads
    __shared__ float2 sP[2][KK][256];    // cross-group reduce, 36 KB

    if (tid < HH * 7) sW1[tid] = W1[tid];
    if (tid < HH)     { sb1[tid] = pb1[tid]; sW2[tid] = W2[tid]; }
    if (tid < KK * 3) sE[tid / 3][tid % 3] = c_epos[tid / 3][tid % 3] + eoff[b * KK * 3 + tid];
    if (tid == 0)     sb2 = pb2[0];

    // ---- env register prefetch (independent of MLP -> overlaps it) ----
    const float2* envp = (const float2*)(env + ((size_t)(b * NN + n0 + ng * 16)) * TT) + tp;
    float2 pf[8];
    #pragma unroll
    for (int i = 0; i < 8; ++i) pf[i] = envp[(size_t)i * (TT / 2)];

    __syncthreads();   // weights + sE visible

    if (tid < NPER * KK) {           // 288 MLP evals, one per thread, 1x total
        const int k  = tid % KK;
        const int nl = tid / KK;
        const int bn = b * NN + n0 + nl;

        const float px = pos[bn * 3 + 0];
        const float py = pos[bn * 3 + 1];
        const float pz = pos[bn * 3 + 2];

        const float rx = sE[k][0] - px, ry = sE[k][1] - py, rz = sE[k][2] - pz;
        const float r2 = rx * rx + ry * ry + rz * rz;
        const float d0 = r2 + 0.04f;
        const float denom = d0 * sqrtf(d0);

        const float rdist = fmaxf(sqrtf(r2), 1e-6f);
        const float rinv  = 1.0f / rdist;
        float feat[7];
        feat[0] = px; feat[1] = py; feat[2] = pz;
        feat[3] = rx * rinv; feat[4] = ry * rinv; feat[5] = rz * rinv;
        feat[6] = rdist;

        float raw = sb2;
        #pragma unroll
        for (int j = 0; j < HH; ++j) {
            float s = sb1[j];
            #pragma unroll
            for (int f = 0; f < 7; ++f) s += sW1[j * 7 + f] * feat[f];
            const float g = 0.5f * s * (1.0f + erff(s * 0.70710678118654752f));
            raw += sW2[j] * g;
        }
        const float corr = 1.0f + 0.5f * tanhf(raw);

        const float ddx = dd[bn * 3 + 0], ddy = dd[bn * 3 + 1], ddz = dd[bn * 3 + 2];
        const float dot = ddx * rx + ddy * ry + ddz * rz;

        sA[nl][k] = amp[bn] * dot * corr / denom;
    }
    __syncthreads();

    // ---- main loop: 16 n rows for this group, fully unrolled ----
    float2 acc[KK];
    #pragma unroll
    for (int k = 0; k < KK; ++k) { acc[k].x = 0.0f; acc[k].y = 0.0f; }

    const float4* s4 = (const float4*)sA;
    #pragma unroll
    for (int i = 0; i < 16; ++i) {
        const int nl = ng * 16 + i;
        const float2 ev = (i < 8) ? pf[i] : envp[(size_t)i * (TT / 2)];
        const float4 a0 = s4[nl * 3 + 0];
        const float4 a1 = s4[nl * 3 + 1];
        const float  a8 = sA[nl][8];
        acc[0].x += a0.x * ev.x; acc[0].y += a0.x * ev.y;
        acc[1].x += a0.y * ev.x; acc[1].y += a0.y * ev.y;
        acc[2].x += a0.z * ev.x; acc[2].y += a0.z * ev.y;
        acc[3].x += a0.w * ev.x; acc[3].y += a0.w * ev.y;
        acc[4].x += a1.x * ev.x; acc[4].y += a1.x * ev.y;
        acc[5].x += a1.y * ev.x; acc[5].y += a1.y * ev.y;
        acc[6].x += a1.z * ev.x; acc[6].y += a1.z * ev.y;
        acc[7].x += a1.w * ev.x; acc[7].y += a1.w * ev.y;
        acc[8].x += a8   * ev.x; acc[8].y += a8   * ev.y;
    }

    #pragma unroll
    for (int k = 0; k < KK; ++k) sP[ng][k][tp] = acc[k];
    __syncthreads();

    // ---- group 0's threads fold the two halves and write partial ----
    if (tid < 256) {
        float2* pp = (float2*)(partial + (((size_t)chunk * BB + b) * KK) * TT) + tp;
        #pragma unroll
        for (int k = 0; k < KK; ++k) {
            const float2 u = sP[0][k][tp];
            const float2 v = sP[1][k][tp];
            float2 w; w.x = u.x + v.x; w.y = u.y + v.y;
            pp[(size_t)k * (TT / 2)] = w;
        }
    }
}

// Finalize: V = clip(sum_c partial, -50, 50); emit leads + V_electrodes.
// grid (16, 8): block covers 32 t; 32 c-groups x 8 float4-slots over t.
__global__ __launch_bounds__(256) void finalize_kernel(
    const float* __restrict__ partial,  // (NCHUNK,B,K,T)
    float* __restrict__ out)            // v_leads (B,12,T) then V_elec (B,K,T)
{
    const int tid = threadIdx.x;
    const int tl4 = tid & 7;        // float4 slot: t = t0 + tl4*4 .. +3
    const int cg  = tid >> 3;       // 0..31 = chunk
    const int tc  = blockIdx.x;     // 0..15
    const int b   = blockIdx.y;
    const int t0  = tc * 32;

    float4 s[KK];
    {
        const float* base = partial + (((size_t)cg * BB + b) * KK) * TT + t0 + tl4 * 4;
        #pragma unroll
        for (int k = 0; k < KK; ++k)
            s[k] = *(const float4*)(base + (size_t)k * TT);
    }

    __shared__ float4 sV[32][KK][8];   // 36 KB
    __shared__ float  sRf[KK][32];
    #pragma unroll
    for (int k = 0; k < KK; ++k) sV[cg][k][tl4] = s[k];
    __syncthreads();

    if (tid < KK * 8) {                // 72 threads: reduce 32 chunks
        const int k  = tid >> 3;
        const int tl = tid & 7;
        float4 v = make_float4(0.f, 0.f, 0.f, 0.f);
        #pragma unroll
        for (int g = 0; g < 32; ++g) {
            const float4 u = sV[g][k][tl];
            v.x += u.x; v.y += u.y; v.z += u.z; v.w += u.w;
        }
        sRf[k][tl * 4 + 0] = fminf(fmaxf(v.x, -50.0f), 50.0f);
        sRf[k][tl * 4 + 1] = fminf(fmaxf(v.y, -50.0f), 50.0f);
        sRf[k][tl * 4 + 2] = fminf(fmaxf(v.z, -50.0f), 50.0f);
        sRf[k][tl * 4 + 3] = fminf(fmaxf(v.w, -50.0f), 50.0f);
    }
    __syncthreads();

    if (tid < 32) {
        const int t = t0 + tid;
        float V[KK];
        #pragma unroll
        for (int k = 0; k < KK; ++k) V[k] = sRf[k][tid];

        float* vleads = out;                        // (B,12,T)
        float* velec  = out + (size_t)BB * 12 * TT; // (B,K,T)

        #pragma unroll
        for (int k = 0; k < KK; ++k)
            velec[((size_t)b * KK + k) * TT + t] = V[k];

        const float RA = V[0], LA = V[1], LL = V[2];
        const float WCT = (RA + LA + LL) * (1.0f / 3.0f);

        float L[12];
        L[0] = LA - RA;
        L[1] = LL - RA;
        L[2] = LL - LA;
        L[3] = RA - 0.5f * (LA + LL);
        L[4] = LA - 0.5f * (RA + LL);
        L[5] = LL - 0.5f * (RA + LA);
        L[6]  = V[3] - WCT;
        L[7]  = V[4] - WCT;
        L[8]  = V[5] - WCT;
        L[9]  = V[6] - WCT;
        L[10] = V[7] - WCT;
        L[11] = V[8] - WCT;

        #pragma unroll
        for (int l = 0; l < 12; ++l)
            vleads[((size_t)b * 12 + l) * TT + t] = L[l];
    }
}

extern "C" void kernel_launch(void* const* d_in, const int* in_sizes, int n_in,
                              void* d_out, int out_size, void* d_ws, size_t ws_size,
                              hipStream_t stream) {
    const float* pos  = (const float*)d_in[0];
    const float* dd   = (const float*)d_in[1];
    const float* amp  = (const float*)d_in[2];
    const float* env  = (const float*)d_in[3];
    const float* eoff = (const float*)d_in[4];
    const float* W1   = (const float*)d_in[5];
    const float* b1   = (const float*)d_in[6];
    const float* W2   = (const float*)d_in[7];
    const float* b2   = (const float*)d_in[8];
    float* out = (float*)d_out;

    float* partial = (float*)d_ws;   // (NCHUNK,B,K,T) floats = 4.7 MB

    {
        dim3 grid(NCHUNK, BB);           // 32 x 8 = 256 blocks, 512 threads
        fused_kernel<<<grid, 512, 0, stream>>>(
            pos, dd, amp, env, eoff, W1, b1, W2, b2, partial);
    }
    {
        dim3 grid(16, BB);               // 128 blocks
        finalize_kernel<<<grid, 256, 0, stream>>>(partial, out);
    }
}